// Round 4
// baseline (176.650 us; speedup 1.0000x reference)
//
#include <hip/hip_runtime.h>

#define BB 32
#define CC 768
#define SS 1024
#define LLn 77
#define DD 512
#define LP 80      // padded L for f32 u buffer / tlc rows
#define LP2 96     // padded L (K dim) for bf16 MFMA operands, mult of 32
#define MROWS 2464 // B * L = 32 * 77
#define AS_STR 520 // halves, LDS stride for staged A rows (2-way banks)
#define QH_STR 104 // halves, LDS stride for qh rows (2-way banks)

#define RATIO 0.0751953125f   // 77/1024 exact in fp32
#define IRATIO 13.298701f     // ~1024/77 (only used for conservative loop bounds)

typedef short bf16x8 __attribute__((ext_vector_type(8)));
typedef float f32x4 __attribute__((ext_vector_type(4)));
typedef unsigned short u16;

__device__ __forceinline__ float bf2f(unsigned int h16) {
    unsigned int u = h16 << 16;
    float f; __builtin_memcpy(&f, &u, 4); return f;
}
__device__ __forceinline__ u16 f2bf(float f) {
    unsigned int u; __builtin_memcpy(&u, &f, 4);
    u += 0x7fffu + ((u >> 16) & 1u);   // RNE
    return (u16)(u >> 16);
}

// Convert + transpose W [D,C] f32 -> Wb [C,D] bf16 (B operand rows)
__global__ __launch_bounds__(256) void k_cvt_w(const float* __restrict__ Wt,
                                               u16* __restrict__ Wb) {
    __shared__ float tile[32][33];
    const int c0 = blockIdx.x * 32, d0 = blockIdx.y * 32;
    const int tx = threadIdx.x & 31, ty = threadIdx.x >> 5;  // ty 0..7
#pragma unroll
    for (int k = 0; k < 4; ++k) {
        int d = ty + k * 8;
        tile[d][tx] = Wt[(size_t)(d0 + d) * CC + c0 + tx];
    }
    __syncthreads();
#pragma unroll
    for (int k = 0; k < 4; ++k) {
        int c = ty + k * 8;
        Wb[(size_t)(c0 + c) * DD + d0 + tx] = f2bf(tile[tx][c]);
    }
}

// K1 (MFMA, fused text->bf16 + pad): t = text @ W over flattened rows g = b*77+l.
// Grid 154; 4 waves/block; each wave: 192 cols x 16 rows; K=512.
__global__ __launch_bounds__(256) void k_tgemm_mfma(const float* __restrict__ text,
                                                    const u16* __restrict__ Wb,
                                                    u16* __restrict__ tc,
                                                    u16* __restrict__ tlc) {
    __shared__ u16 As[16 * AS_STR];   // 16640 B
    const int tid = threadIdx.x;
    const int g0 = blockIdx.x * 16;
    for (int i4 = tid; i4 < 2048; i4 += 256) {
        int r = i4 >> 7, col4 = (i4 & 127) << 2;
        float4 v = *reinterpret_cast<const float4*>(&text[(size_t)(g0 + r) * DD + col4]);
        u16 o[4] = {f2bf(v.x), f2bf(v.y), f2bf(v.z), f2bf(v.w)};
        *reinterpret_cast<uint2*>(&As[r * AS_STR + col4]) = *reinterpret_cast<uint2*>(o);
    }
    __syncthreads();

    const int w = tid >> 6, lane = tid & 63;
    const int lm = lane & 15, lg = lane >> 4;
    const int c0 = w * 192;

    f32x4 acc[12];
#pragma unroll
    for (int nt = 0; nt < 12; ++nt) acc[nt] = (f32x4){0.f, 0.f, 0.f, 0.f};

    const u16* bp = Wb + (size_t)(c0 + lm) * DD + lg * 8;
#pragma unroll 2
    for (int ks = 0; ks < 16; ++ks) {
        bf16x8 aq = *reinterpret_cast<const bf16x8*>(&As[lm * AS_STR + ks * 32 + lg * 8]);
#pragma unroll
        for (int nt = 0; nt < 12; ++nt) {
            bf16x8 bv = *reinterpret_cast<const bf16x8*>(bp + (size_t)nt * 16 * DD + ks * 32);
            acc[nt] = __builtin_amdgcn_mfma_f32_16x16x32_bf16(aq, bv, acc[nt], 0, 0, 0);
        }
    }
#pragma unroll
    for (int r = 0; r < 4; ++r) {
        int g = g0 + lg * 4 + r;
        int b = g / 77, l = g - b * 77;
#pragma unroll
        for (int nt = 0; nt < 12; ++nt) {
            int c = c0 + nt * 16 + lm;
            u16 v = f2bf(acc[nt][r]);
            tc[((size_t)b * CC + c) * LP2 + l] = v;
            tlc[((size_t)b * LP + l) * CC + c] = v;
        }
        if (l == 76) {  // this block owns batch b's last row: zero pad regions
#pragma unroll
            for (int nt = 0; nt < 12; ++nt) {
                int c = c0 + nt * 16 + lm;
                for (int pp = LLn; pp < LP2; ++pp) tc[((size_t)b * CC + c) * LP2 + pp] = 0;
#pragma unroll
                for (int pp = LLn; pp < LP; ++pp) tlc[((size_t)b * LP + pp) * CC + c] = 0;
            }
        }
    }
}

// K3: fused qh-build + MFMA attention: logits(16x768) -> softmax -> u (16x80)
// 4 waves/block; waves share the 16 rows, each wave owns a 192-col j-slice.
__global__ __launch_bounds__(256, 2) void k_attn(const float* __restrict__ q,
                                                 const u16* __restrict__ tc,
                                                 const u16* __restrict__ tlc,
                                                 float* __restrict__ u_ws) {
    __shared__ float qs[4 * 1028];                 // 16448 B (chunk staging)
    __shared__ u16 qh_lds[16 * QH_STR];            // 3328 B
    __shared__ float pmax[4][16];
    __shared__ float psum[4][16];
    __shared__ float invl[16];
    __shared__ __align__(16) char pbuf[4][6400];   // per-wave: P bf16 [16][200] / u f32 [16][81]

    const int b = blockIdx.y;
    const int iBase = blockIdx.x * 16;
    const int tid = threadIdx.x;
    const int w = tid >> 6, lane = tid & 63;
    const int lm = lane & 15, lg = lane >> 4;

    // ---- prologue: build qh[16][96] bf16 in LDS from q (4 rows per chunk) ----
    for (int chunk = 0; chunk < 4; ++chunk) {
        for (int i = tid; i < 1024; i += 256) {
            int r = i >> 8, col4 = (i & 255) << 2;
            *reinterpret_cast<float4*>(&qs[r * 1028 + col4]) =
                *reinterpret_cast<const float4*>(&q[((size_t)b * CC + iBase + chunk * 4 + r) * SS + col4]);
        }
        __syncthreads();
        for (int idx = tid; idx < 4 * LP2; idx += 256) {
            int r = idx / LP2, l = idx % LP2;
            float val = 0.f;
            if (l < LLn) {
                int s_lo = max(0, (int)floorf(((float)l - 0.5f) * IRATIO - 0.5f) - 1);
                int s_hi = min(SS - 1, (int)ceilf(((float)l + 1.5f) * IRATIO - 0.5f) + 1);
                float a = 0.f;
                for (int s = s_lo; s <= s_hi; ++s) {
                    float src = fmaf((float)s + 0.5f, RATIO, -0.5f);
                    src = fminf(fmaxf(src, 0.f), 76.f);
                    int i0 = (int)src;
                    float wgt = src - (float)i0;
                    int i1 = (i0 < 76) ? i0 + 1 : 76;
                    float qv = qs[r * 1028 + s];
                    if (i0 == l) a = fmaf(1.f - wgt, qv, a);
                    if (i1 == l) a = fmaf(wgt, qv, a);
                }
                val = a * 0.03125f;   // fold 1024^-0.5
            }
            qh_lds[(chunk * 4 + r) * QH_STR + l] = f2bf(val);
        }
        __syncthreads();
    }

    // ---- logits: A = qh rows (3 k-steps), B = tc rows of this wave's j-slice ----
    bf16x8 aq0 = *reinterpret_cast<const bf16x8*>(&qh_lds[lm * QH_STR + lg * 8]);
    bf16x8 aq1 = *reinterpret_cast<const bf16x8*>(&qh_lds[lm * QH_STR + 32 + lg * 8]);
    bf16x8 aq2 = *reinterpret_cast<const bf16x8*>(&qh_lds[lm * QH_STR + 64 + lg * 8]);

    f32x4 acc[12];
#pragma unroll
    for (int t = 0; t < 12; ++t) acc[t] = (f32x4){0.f, 0.f, 0.f, 0.f};

    const u16* tcb = tc + ((size_t)b * CC + w * 192 + lm) * LP2 + lg * 8;
#pragma unroll
    for (int t = 0; t < 12; ++t) {
        const u16* p = tcb + (size_t)t * 16 * LP2;
        bf16x8 b0 = *reinterpret_cast<const bf16x8*>(p);
        bf16x8 b1 = *reinterpret_cast<const bf16x8*>(p + 32);
        bf16x8 b2 = *reinterpret_cast<const bf16x8*>(p + 64);
        acc[t] = __builtin_amdgcn_mfma_f32_16x16x32_bf16(aq0, b0, acc[t], 0, 0, 0);
        acc[t] = __builtin_amdgcn_mfma_f32_16x16x32_bf16(aq1, b1, acc[t], 0, 0, 0);
        acc[t] = __builtin_amdgcn_mfma_f32_16x16x32_bf16(aq2, b2, acc[t], 0, 0, 0);
    }

    // ---- softmax (C layout: col = lane&15, row = lg*4 + reg) ----
    float m[4];
#pragma unroll
    for (int r = 0; r < 4; ++r) {
        float mm = acc[0][r];
#pragma unroll
        for (int t = 1; t < 12; ++t) mm = fmaxf(mm, acc[t][r]);
#pragma unroll
        for (int off = 8; off >= 1; off >>= 1) mm = fmaxf(mm, __shfl_xor(mm, off));
        m[r] = mm;
    }
    if (lm == 0) {
#pragma unroll
        for (int r = 0; r < 4; ++r) pmax[w][lg * 4 + r] = m[r];
    }
    __syncthreads();
    float gm[4];
#pragma unroll
    for (int r = 0; r < 4; ++r) {
        int row = lg * 4 + r;
        gm[r] = fmaxf(fmaxf(pmax[0][row], pmax[1][row]), fmaxf(pmax[2][row], pmax[3][row]));
    }
    float s[4] = {0.f, 0.f, 0.f, 0.f};
#pragma unroll
    for (int t = 0; t < 12; ++t) {
#pragma unroll
        for (int r = 0; r < 4; ++r) {
            float e = __expf(acc[t][r] - gm[r]);
            acc[t][r] = e;
            s[r] += e;
        }
    }
#pragma unroll
    for (int r = 0; r < 4; ++r) {
#pragma unroll
        for (int off = 8; off >= 1; off >>= 1) s[r] += __shfl_xor(s[r], off);
    }
    if (lm == 0) {
#pragma unroll
        for (int r = 0; r < 4; ++r) psum[w][lg * 4 + r] = s[r];
    }
    __syncthreads();
    if (w == 0 && lm == 0) {
#pragma unroll
        for (int r = 0; r < 4; ++r) {
            int row = lg * 4 + r;
            invl[row] = 1.0f / (psum[0][row] + psum[1][row] + psum[2][row] + psum[3][row]);
        }
    }

    // ---- P -> bf16 into per-wave LDS (stride 200 halves) ----
    u16* P = (u16*)pbuf[w];
#pragma unroll
    for (int t = 0; t < 12; ++t) {
#pragma unroll
        for (int r = 0; r < 4; ++r)
            P[(lg * 4 + r) * 200 + t * 16 + lm] = f2bf(acc[t][r]);
    }

    // ---- PV: u[16 x 80] += P[16 x 192] . tlc[192 x 80] ----
    f32x4 u[5];
#pragma unroll
    for (int nt = 0; nt < 5; ++nt) u[nt] = (f32x4){0.f, 0.f, 0.f, 0.f};
    const u16* tb = tlc + ((size_t)b * LP + lm) * CC + w * 192 + lg * 8;
#pragma unroll
    for (int ks = 0; ks < 6; ++ks) {
        bf16x8 pa = *reinterpret_cast<const bf16x8*>(&P[lm * 200 + ks * 32 + lg * 8]);
#pragma unroll
        for (int nt = 0; nt < 5; ++nt) {
            bf16x8 bv = *reinterpret_cast<const bf16x8*>(tb + (size_t)nt * 16 * CC + ks * 32);
            u[nt] = __builtin_amdgcn_mfma_f32_16x16x32_bf16(pa, bv, u[nt], 0, 0, 0);
        }
    }

    // ---- cross-wave u reduce (alias P buffer; wave-local reuse is ordered) ----
    float* up = (float*)pbuf[w];
#pragma unroll
    for (int nt = 0; nt < 5; ++nt) {
#pragma unroll
        for (int r = 0; r < 4; ++r)
            up[(lg * 4 + r) * 81 + nt * 16 + lm] = u[nt][r];
    }
    __syncthreads();
#pragma unroll
    for (int k = 0; k < 5; ++k) {
        int idx = tid + (k << 8);
        int row = idx / LP, l = idx % LP;
        float v = ((float*)pbuf[0])[row * 81 + l] + ((float*)pbuf[1])[row * 81 + l]
                + ((float*)pbuf[2])[row * 81 + l] + ((float*)pbuf[3])[row * 81 + l];
        u_ws[((size_t)b * CC + iBase + row) * LP + l] = v * invl[row];
    }
}

// K4: out = q + gamma * interp(u)
__global__ __launch_bounds__(256) void k_out(const float* __restrict__ q,
                                             const float* __restrict__ u_ws,
                                             const float* __restrict__ gamma,
                                             float* __restrict__ out) {
    __shared__ float us[LP];
    const int b = blockIdx.y;
    const int c = blockIdx.x;
    const int tid = threadIdx.x;
    if (tid < LLn) us[tid] = u_ws[((size_t)b * CC + c) * LP + tid];
    __syncthreads();
    const float g = gamma[0];
    const int base = (b * CC + c) * SS + tid * 4;
    float4 qv = *reinterpret_cast<const float4*>(&q[base]);
    float rr[4];
    const float* qp = reinterpret_cast<const float*>(&qv);
#pragma unroll
    for (int k = 0; k < 4; ++k) {
        int s = tid * 4 + k;
        float src = fmaf((float)s + 0.5f, RATIO, -0.5f);
        src = fminf(fmaxf(src, 0.f), 76.f);
        int i0 = (int)src;
        float w = src - (float)i0;
        int i1 = (i0 < 76) ? i0 + 1 : 76;
        float uv = fmaf(1.f - w, us[i0], w * us[i1]);
        rr[k] = qp[k] + g * uv;
    }
    *reinterpret_cast<float4*>(&out[base]) = make_float4(rr[0], rr[1], rr[2], rr[3]);
}

extern "C" void kernel_launch(void* const* d_in, const int* in_sizes, int n_in,
                              void* d_out, int out_size, void* d_ws, size_t ws_size,
                              hipStream_t stream) {
    const float* img   = (const float*)d_in[0];
    const float* text  = (const float*)d_in[1];
    const float* Wt    = (const float*)d_in[2];
    const float* gamma = (const float*)d_in[3];
    float* out = (float*)d_out;
    char* ws = (char*)d_ws;
    u16*   tc_bf  = (u16*)(ws);                   // 32*768*96*2 = 4,718,592
    u16*   tlc_bf = (u16*)(ws + 4718592);         // 32*80*768*2 = 3,932,160
    float* u_ws   = (float*)(ws + 8650752);       // 32*768*80*4 = 7,864,320
    u16*   Wb_bf  = (u16*)(ws + 16515072);        // 768*512*2   =   786,432

    k_cvt_w<<<dim3(CC / 32, DD / 32), 256, 0, stream>>>(Wt, Wb_bf);
    k_tgemm_mfma<<<dim3(MROWS / 16), 256, 0, stream>>>(text, Wb_bf, tc_bf, tlc_bf);
    k_attn<<<dim3(48, BB), 256, 0, stream>>>(img, tc_bf, tlc_bf, u_ws);
    k_out <<<dim3(CC, BB), 256, 0, stream>>>(img, u_ws, gamma, out);
}

// Round 5
// 137.731 us; speedup vs baseline: 1.2826x; 1.2826x over previous
//
#include <hip/hip_runtime.h>

#define BB 32
#define CC 768
#define SS 1024
#define LLn 77
#define DD 512
#define LP 80      // padded L for f32 u buffer / tlc rows / At rows
#define LP2 96     // padded L (K dim) for bf16 MFMA operands, mult of 32

#define RATIO 0.0751953125f   // 77/1024 exact in fp32
#define IRATIO 13.298701f     // ~1024/77 (only used for conservative loop bounds)

#define QH_BLOCKS (256 * BB)          // 8192
#define CVT_TXT_BLOCKS (BB * LP * DD / 4 / 256)   // 1280
#define CVT_W_BLOCKS ((CC / 32) * (DD / 32))      // 384

typedef short bf16x8 __attribute__((ext_vector_type(8)));
typedef float f32x4 __attribute__((ext_vector_type(4)));
typedef unsigned short u16;

__device__ __forceinline__ float bf2f(unsigned int h16) {
    unsigned int u = h16 << 16;
    float f; __builtin_memcpy(&f, &u, 4); return f;
}
__device__ __forceinline__ u16 f2bf(float f) {
    unsigned int u; __builtin_memcpy(&u, &f, 4);
    u += 0x7fffu + ((u >> 16) & 1u);   // RNE
    return (u16)(u >> 16);
}

// K0 (fused prep): qh-interp (8192 blocks) | text->bf16 padded (1280) | W transpose->bf16 (384)
__global__ __launch_bounds__(256) void k_prep(const float* __restrict__ q,
                                              const float* __restrict__ text,
                                              const float* __restrict__ Wt,
                                              u16* __restrict__ qh,
                                              u16* __restrict__ At,
                                              u16* __restrict__ Wb) {
    __shared__ float smem[3 * 1024];   // qs for qh part; tile[32][33] for cvt_w part
    const int bx = blockIdx.x;
    const int tid = threadIdx.x;

    if (bx < QH_BLOCKS) {
        // ---- qh[b,c,l] = (sum_s A[s,l] * q[b,c,s]) * S^-0.5 ----
        const int b = bx >> 8;
        const int c0 = (bx & 255) * 3;
        for (int i4 = tid; i4 < 3 * 256; i4 += 256) {
            int r = i4 >> 8, col = (i4 & 255) << 2;
            *reinterpret_cast<float4*>(&smem[r * 1024 + col]) =
                *reinterpret_cast<const float4*>(&q[((size_t)b * CC + c0 + r) * SS + col]);
        }
        __syncthreads();
        for (int idx = tid; idx < 3 * LP2; idx += 256) {
            int r = idx / LP2, l = idx % LP2;
            float val = 0.f;
            if (l < LLn) {
                int s_lo = max(0, (int)floorf(((float)l - 0.5f) * IRATIO - 0.5f) - 1);
                int s_hi = min(SS - 1, (int)ceilf(((float)l + 1.5f) * IRATIO - 0.5f) + 1);
                float a = 0.f;
                for (int s = s_lo; s <= s_hi; ++s) {
                    float src = fmaf((float)s + 0.5f, RATIO, -0.5f);
                    src = fminf(fmaxf(src, 0.f), 76.f);
                    int i0 = (int)src;
                    float w = src - (float)i0;
                    int i1 = (i0 < 76) ? i0 + 1 : 76;
                    float qv = smem[r * 1024 + s];
                    if (i0 == l) a = fmaf(1.f - w, qv, a);
                    if (i1 == l) a = fmaf(w, qv, a);
                }
                val = a * 0.03125f;   // fold 1024^-0.5
            }
            qh[((size_t)b * CC + c0 + r) * LP2 + l] = f2bf(val);
        }
    } else if (bx < QH_BLOCKS + CVT_TXT_BLOCKS) {
        // ---- At[b,80,512] bf16 (rows 77..79 zero) from text[b,77,512] f32 ----
        int j = (bx - QH_BLOCKS) * 256 + tid;      // float4-granular, exactly covers
        int row80 = j >> 7, col4 = (j & 127) << 2;
        int b = row80 / LP, l = row80 - b * LP;
        u16 o[4] = {0, 0, 0, 0};
        if (l < LLn) {
            float4 v = *reinterpret_cast<const float4*>(&text[((size_t)b * LLn + l) * DD + col4]);
            o[0] = f2bf(v.x); o[1] = f2bf(v.y); o[2] = f2bf(v.z); o[3] = f2bf(v.w);
        }
        *reinterpret_cast<uint2*>(&At[(size_t)row80 * DD + col4]) = *reinterpret_cast<uint2*>(o);
    } else {
        // ---- Wb[c,d] bf16 = W[d,c] transposed ----
        const int bw = bx - QH_BLOCKS - CVT_TXT_BLOCKS;
        const int c0 = (bw % (CC / 32)) * 32, d0 = (bw / (CC / 32)) * 32;
        const int tx = tid & 31, ty = tid >> 5;    // ty 0..7
#pragma unroll
        for (int k = 0; k < 4; ++k) {
            int d = ty + k * 8;
            smem[d * 33 + tx] = Wt[(size_t)(d0 + d) * CC + c0 + tx];
        }
        __syncthreads();
#pragma unroll
        for (int k = 0; k < 4; ++k) {
            int c = ty + k * 8;
            Wb[(size_t)(c0 + c) * DD + d0 + tx] = f2bf(smem[tx * 33 + c]);
        }
    }
}

// K1 (MFMA): t = text @ W per batch-aligned tile. Grid (160, 4): bx = b*5 + tile.
// 4 waves/block; each wave 48 cols x 16 rows; K=512. Aligned uint2 tc stores; tile 4 writes pads.
__global__ __launch_bounds__(256) void k_tgemm_mfma(const u16* __restrict__ At,
                                                    const u16* __restrict__ Wb,
                                                    u16* __restrict__ tc,
                                                    u16* __restrict__ tlc) {
    const int tid = threadIdx.x;
    const int w = tid >> 6, lane = tid & 63;
    const int lm = lane & 15, lg = lane >> 4;
    const int b = blockIdx.x / 5, tile = blockIdx.x % 5;
    const int l0 = tile * 16;
    const int c0 = blockIdx.y * 192 + w * 48;

    f32x4 acc[3];
#pragma unroll
    for (int nt = 0; nt < 3; ++nt) acc[nt] = (f32x4){0.f, 0.f, 0.f, 0.f};

    const u16* ap = At + ((size_t)b * LP + l0 + lm) * DD + lg * 8;
    const u16* bp = Wb + (size_t)(c0 + lm) * DD + lg * 8;
#pragma unroll 4
    for (int ks = 0; ks < 16; ++ks) {
        bf16x8 aq = *reinterpret_cast<const bf16x8*>(ap + ks * 32);
#pragma unroll
        for (int nt = 0; nt < 3; ++nt) {
            bf16x8 bv = *reinterpret_cast<const bf16x8*>(bp + (size_t)nt * 16 * DD + ks * 32);
            acc[nt] = __builtin_amdgcn_mfma_f32_16x16x32_bf16(aq, bv, acc[nt], 0, 0, 0);
        }
    }

    const int lq = l0 + lg * 4;   // quad start, multiple of 4 (pad rows give zero acc)
#pragma unroll
    for (int nt = 0; nt < 3; ++nt) {
        int c = c0 + nt * 16 + lm;
        u16 pk[4];
#pragma unroll
        for (int r = 0; r < 4; ++r) pk[r] = f2bf(acc[nt][r]);
        uint2 pv; __builtin_memcpy(&pv, pk, 8);
        *reinterpret_cast<uint2*>(&tc[((size_t)b * CC + c) * LP2 + lq]) = pv;  // 8B aligned
#pragma unroll
        for (int r = 0; r < 4; ++r)
            tlc[((size_t)b * LP + lq + r) * CC + c] = pk[r];
    }
    if (tile == 4) {   // zero tc K-pad l=80..95 (aligned 16B stores)
        uint4 z = {0u, 0u, 0u, 0u};
#pragma unroll
        for (int nt = 0; nt < 3; ++nt) {
            int c = c0 + nt * 16 + lm;
            if (lg == 0) {
                *reinterpret_cast<uint4*>(&tc[((size_t)b * CC + c) * LP2 + 80]) = z;
                *reinterpret_cast<uint4*>(&tc[((size_t)b * CC + c) * LP2 + 88]) = z;
            }
        }
    }
}

// K3: MFMA fused attention: logits(16x768) -> softmax -> u = attn . t (16x80)
// 4 waves/block; all waves share the 16 rows, each wave owns a 192-col j-slice.
__global__ __launch_bounds__(256, 2) void k_attn(const u16* __restrict__ qh,
                                                 const u16* __restrict__ tc,
                                                 const u16* __restrict__ tlc,
                                                 float* __restrict__ u_ws) {
    __shared__ float pmax[4][16];
    __shared__ float psum[4][16];
    __shared__ float invl[16];
    __shared__ __align__(16) char pbuf[4][6400];   // per-wave: P bf16 [16][200] / u f32 [16][81]

    const int b = blockIdx.y;
    const int iBase = blockIdx.x * 16;
    const int tid = threadIdx.x;
    const int w = tid >> 6, lane = tid & 63;
    const int lm = lane & 15, lg = lane >> 4;

    // ---- logits: A = qh rows (3 k-steps), B = tc rows of this wave's j-slice ----
    const u16* qbase = qh + ((size_t)b * CC + iBase + lm) * LP2 + lg * 8;
    bf16x8 aq0 = *reinterpret_cast<const bf16x8*>(qbase);
    bf16x8 aq1 = *reinterpret_cast<const bf16x8*>(qbase + 32);
    bf16x8 aq2 = *reinterpret_cast<const bf16x8*>(qbase + 64);

    f32x4 acc[12];
#pragma unroll
    for (int t = 0; t < 12; ++t) acc[t] = (f32x4){0.f, 0.f, 0.f, 0.f};

    const u16* tcb = tc + ((size_t)b * CC + w * 192 + lm) * LP2 + lg * 8;
#pragma unroll
    for (int t = 0; t < 12; ++t) {
        const u16* p = tcb + (size_t)t * 16 * LP2;
        bf16x8 b0 = *reinterpret_cast<const bf16x8*>(p);
        bf16x8 b1 = *reinterpret_cast<const bf16x8*>(p + 32);
        bf16x8 b2 = *reinterpret_cast<const bf16x8*>(p + 64);
        acc[t] = __builtin_amdgcn_mfma_f32_16x16x32_bf16(aq0, b0, acc[t], 0, 0, 0);
        acc[t] = __builtin_amdgcn_mfma_f32_16x16x32_bf16(aq1, b1, acc[t], 0, 0, 0);
        acc[t] = __builtin_amdgcn_mfma_f32_16x16x32_bf16(aq2, b2, acc[t], 0, 0, 0);
    }

    // ---- softmax (C layout: col = lane&15, row = lg*4 + reg) ----
    float m[4];
#pragma unroll
    for (int r = 0; r < 4; ++r) {
        float mm = acc[0][r];
#pragma unroll
        for (int t = 1; t < 12; ++t) mm = fmaxf(mm, acc[t][r]);
#pragma unroll
        for (int off = 8; off >= 1; off >>= 1) mm = fmaxf(mm, __shfl_xor(mm, off));
        m[r] = mm;
    }
    if (lm == 0) {
#pragma unroll
        for (int r = 0; r < 4; ++r) pmax[w][lg * 4 + r] = m[r];
    }
    __syncthreads();
    float gm[4];
#pragma unroll
    for (int r = 0; r < 4; ++r) {
        int row = lg * 4 + r;
        gm[r] = fmaxf(fmaxf(pmax[0][row], pmax[1][row]), fmaxf(pmax[2][row], pmax[3][row]));
    }
    float s[4] = {0.f, 0.f, 0.f, 0.f};
#pragma unroll
    for (int t = 0; t < 12; ++t) {
#pragma unroll
        for (int r = 0; r < 4; ++r) {
            float e = __expf(acc[t][r] - gm[r]);
            acc[t][r] = e;
            s[r] += e;
        }
    }
#pragma unroll
    for (int r = 0; r < 4; ++r) {
#pragma unroll
        for (int off = 8; off >= 1; off >>= 1) s[r] += __shfl_xor(s[r], off);
    }
    if (lm == 0) {
#pragma unroll
        for (int r = 0; r < 4; ++r) psum[w][lg * 4 + r] = s[r];
    }
    __syncthreads();
    if (w == 0 && lm == 0) {
#pragma unroll
        for (int r = 0; r < 4; ++r) {
            int row = lg * 4 + r;
            invl[row] = 1.0f / (psum[0][row] + psum[1][row] + psum[2][row] + psum[3][row]);
        }
    }

    // ---- P -> bf16 into per-wave LDS (stride 200 halves) ----
    u16* P = (u16*)pbuf[w];
#pragma unroll
    for (int t = 0; t < 12; ++t) {
#pragma unroll
        for (int r = 0; r < 4; ++r)
            P[(lg * 4 + r) * 200 + t * 16 + lm] = f2bf(acc[t][r]);
    }

    // ---- PV: u[16 x 80] += P[16 x 192] . tlc[192 x 80] ----
    f32x4 u[5];
#pragma unroll
    for (int nt = 0; nt < 5; ++nt) u[nt] = (f32x4){0.f, 0.f, 0.f, 0.f};
    const u16* tb = tlc + ((size_t)b * LP + lm) * CC + w * 192 + lg * 8;
#pragma unroll
    for (int ks = 0; ks < 6; ++ks) {
        bf16x8 pa = *reinterpret_cast<const bf16x8*>(&P[lm * 200 + ks * 32 + lg * 8]);
#pragma unroll
        for (int nt = 0; nt < 5; ++nt) {
            bf16x8 bv = *reinterpret_cast<const bf16x8*>(tb + (size_t)nt * 16 * CC + ks * 32);
            u[nt] = __builtin_amdgcn_mfma_f32_16x16x32_bf16(pa, bv, u[nt], 0, 0, 0);
        }
    }

    // ---- cross-wave u reduce (alias P buffer; wave-local reuse is ordered) ----
    float* up = (float*)pbuf[w];
#pragma unroll
    for (int nt = 0; nt < 5; ++nt) {
#pragma unroll
        for (int r = 0; r < 4; ++r)
            up[(lg * 4 + r) * 81 + nt * 16 + lm] = u[nt][r];
    }
    __syncthreads();
#pragma unroll
    for (int k = 0; k < 5; ++k) {
        int idx = tid + (k << 8);
        int row = idx / LP, l = idx % LP;
        float v = ((float*)pbuf[0])[row * 81 + l] + ((float*)pbuf[1])[row * 81 + l]
                + ((float*)pbuf[2])[row * 81 + l] + ((float*)pbuf[3])[row * 81 + l];
        u_ws[((size_t)b * CC + iBase + row) * LP + l] = v * invl[row];
    }
}

// K4: out = q + gamma * interp(u)
__global__ __launch_bounds__(256) void k_out(const float* __restrict__ q,
                                             const float* __restrict__ u_ws,
                                             const float* __restrict__ gamma,
                                             float* __restrict__ out) {
    __shared__ float us[LP];
    const int b = blockIdx.y;
    const int c = blockIdx.x;
    const int tid = threadIdx.x;
    if (tid < LLn) us[tid] = u_ws[((size_t)b * CC + c) * LP + tid];
    __syncthreads();
    const float g = gamma[0];
    const int base = (b * CC + c) * SS + tid * 4;
    float4 qv = *reinterpret_cast<const float4*>(&q[base]);
    float rr[4];
    const float* qp = reinterpret_cast<const float*>(&qv);
#pragma unroll
    for (int k = 0; k < 4; ++k) {
        int s = tid * 4 + k;
        float src = fmaf((float)s + 0.5f, RATIO, -0.5f);
        src = fminf(fmaxf(src, 0.f), 76.f);
        int i0 = (int)src;
        float w = src - (float)i0;
        int i1 = (i0 < 76) ? i0 + 1 : 76;
        float uv = fmaf(1.f - w, us[i0], w * us[i1]);
        rr[k] = qp[k] + g * uv;
    }
    *reinterpret_cast<float4*>(&out[base]) = make_float4(rr[0], rr[1], rr[2], rr[3]);
}

extern "C" void kernel_launch(void* const* d_in, const int* in_sizes, int n_in,
                              void* d_out, int out_size, void* d_ws, size_t ws_size,
                              hipStream_t stream) {
    const float* img   = (const float*)d_in[0];
    const float* text  = (const float*)d_in[1];
    const float* Wt    = (const float*)d_in[2];
    const float* gamma = (const float*)d_in[3];
    float* out = (float*)d_out;
    char* ws = (char*)d_ws;
    u16*   tc_bf  = (u16*)(ws);                   // 32*768*96*2 = 4,718,592
    u16*   tlc_bf = (u16*)(ws + 4718592);         // 32*80*768*2 = 3,932,160
    u16*   qh_bf  = (u16*)(ws + 8650752);         // 32*768*96*2 = 4,718,592
    float* u_ws   = (float*)(ws + 13369344);      // 32*768*80*4 = 7,864,320
    u16*   At_bf  = (u16*)(ws + 21233664);        // 32*80*512*2 = 2,621,440
    u16*   Wb_bf  = (u16*)(ws + 23855104);        // 768*512*2   =   786,432  (end 24,641,536)

    k_prep<<<dim3(QH_BLOCKS + CVT_TXT_BLOCKS + CVT_W_BLOCKS), 256, 0, stream>>>(
        img, text, Wt, qh_bf, At_bf, Wb_bf);
    k_tgemm_mfma<<<dim3(BB * 5, 4), 256, 0, stream>>>(At_bf, Wb_bf, tc_bf, tlc_bf);
    k_attn<<<dim3(48, BB), 256, 0, stream>>>(qh_bf, tc_bf, tlc_bf, u_ws);
    k_out <<<dim3(CC, BB), 256, 0, stream>>>(img, u_ws, gamma, out);
}

// Round 6
// 128.466 us; speedup vs baseline: 1.3751x; 1.0721x over previous
//
#include <hip/hip_runtime.h>

#define BB 32
#define CC 768
#define SS 1024
#define LLn 77
#define DD 512
#define LP 80      // padded L for tlc rows / At rows
#define LP2 96     // padded L (K dim) for bf16 MFMA operands, mult of 32

#define RATIO 0.0751953125f   // 77/1024 exact in fp32
#define IRATIO 13.298701f     // ~1024/77 (only used for conservative loop bounds)

#define CVT_TXT_BLOCKS (BB * LP * DD / 4 / 256)   // 1280
#define CVT_W_BLOCKS ((CC / 32) * (DD / 32))      // 384
#define TG_BLOCKS (BB * 5 * 4)                    // 640
#define QH_BLOCKS (256 * BB)                      // 8192

typedef short bf16x8 __attribute__((ext_vector_type(8)));
typedef float f32x4 __attribute__((ext_vector_type(4)));
typedef unsigned short u16;

__device__ __forceinline__ u16 f2bf(float f) {
    unsigned int u; __builtin_memcpy(&u, &f, 4);
    u += 0x7fffu + ((u >> 16) & 1u);   // RNE
    return (u16)(u >> 16);
}

// K0: tiny converts. text[b,77,512] f32 -> At[b,80,512] bf16 (pad rows zero);
//     W[d,c] f32 -> Wb[c,d] bf16 transposed.
__global__ __launch_bounds__(256) void k_cvt(const float* __restrict__ text,
                                             const float* __restrict__ Wt,
                                             u16* __restrict__ At,
                                             u16* __restrict__ Wb) {
    __shared__ float tile[32 * 33];
    const int bx = blockIdx.x;
    const int tid = threadIdx.x;
    if (bx < CVT_TXT_BLOCKS) {
        int j = bx * 256 + tid;                    // float4-granular, exact cover
        int row80 = j >> 7, col4 = (j & 127) << 2;
        int b = row80 / LP, l = row80 - b * LP;
        u16 o[4] = {0, 0, 0, 0};
        if (l < LLn) {
            float4 v = *reinterpret_cast<const float4*>(&text[((size_t)b * LLn + l) * DD + col4]);
            o[0] = f2bf(v.x); o[1] = f2bf(v.y); o[2] = f2bf(v.z); o[3] = f2bf(v.w);
        }
        *reinterpret_cast<uint2*>(&At[(size_t)row80 * DD + col4]) = *reinterpret_cast<uint2*>(o);
    } else {
        const int bw = bx - CVT_TXT_BLOCKS;
        const int c0 = (bw % (CC / 32)) * 32, d0 = (bw / (CC / 32)) * 32;
        const int tx = tid & 31, ty = tid >> 5;    // ty 0..7
#pragma unroll
        for (int k = 0; k < 4; ++k) {
            int d = ty + k * 8;
            tile[d * 33 + tx] = Wt[(size_t)(d0 + d) * CC + c0 + tx];
        }
        __syncthreads();
#pragma unroll
        for (int k = 0; k < 4; ++k) {
            int c = ty + k * 8;
            Wb[(size_t)(c0 + c) * DD + d0 + tx] = f2bf(tile[tx * 33 + c]);
        }
    }
}

// K1: fused tgemm (640 blocks, first) + qh-interp (8192 blocks). Independent work.
__global__ __launch_bounds__(256) void k_mid(const float* __restrict__ q,
                                             const u16* __restrict__ At,
                                             const u16* __restrict__ Wb,
                                             u16* __restrict__ qh,
                                             u16* __restrict__ tc,
                                             u16* __restrict__ tlc) {
    __shared__ float smem[3 * 1024];
    const int bx = blockIdx.x;
    const int tid = threadIdx.x;

    if (bx < TG_BLOCKS) {
        // ---- t = text @ W, batch-aligned tiles. bx -> (colgroup, b, tile) ----
        const int cg = bx / 160, mt = bx % 160;
        const int b = mt / 5, tile = mt % 5;
        const int l0 = tile * 16;
        const int w = tid >> 6, lane = tid & 63;
        const int lm = lane & 15, lg = lane >> 4;
        const int c0 = cg * 192 + w * 48;

        f32x4 acc[3];
#pragma unroll
        for (int nt = 0; nt < 3; ++nt) acc[nt] = (f32x4){0.f, 0.f, 0.f, 0.f};

        const u16* ap = At + ((size_t)b * LP + l0 + lm) * DD + lg * 8;
        const u16* bp = Wb + (size_t)(c0 + lm) * DD + lg * 8;
#pragma unroll 4
        for (int ks = 0; ks < 16; ++ks) {
            bf16x8 aq = *reinterpret_cast<const bf16x8*>(ap + ks * 32);
#pragma unroll
            for (int nt = 0; nt < 3; ++nt) {
                bf16x8 bv = *reinterpret_cast<const bf16x8*>(bp + (size_t)nt * 16 * DD + ks * 32);
                acc[nt] = __builtin_amdgcn_mfma_f32_16x16x32_bf16(aq, bv, acc[nt], 0, 0, 0);
            }
        }

        const int lq = l0 + lg * 4;   // quad start (pad rows produce zero acc)
#pragma unroll
        for (int nt = 0; nt < 3; ++nt) {
            int c = c0 + nt * 16 + lm;
            u16 pk[4];
#pragma unroll
            for (int r = 0; r < 4; ++r) pk[r] = f2bf(acc[nt][r]);
            uint2 pv; __builtin_memcpy(&pv, pk, 8);
            *reinterpret_cast<uint2*>(&tc[((size_t)b * CC + c) * LP2 + lq]) = pv;  // 8B aligned
#pragma unroll
            for (int r = 0; r < 4; ++r)
                tlc[((size_t)b * LP + lq + r) * CC + c] = pk[r];
        }
        if (tile == 4 && lg == 0) {   // zero tc K-pad l=80..95
            uint4 z = {0u, 0u, 0u, 0u};
#pragma unroll
            for (int nt = 0; nt < 3; ++nt) {
                int c = c0 + nt * 16 + lm;
                *reinterpret_cast<uint4*>(&tc[((size_t)b * CC + c) * LP2 + 80]) = z;
                *reinterpret_cast<uint4*>(&tc[((size_t)b * CC + c) * LP2 + 88]) = z;
            }
        }
    } else {
        // ---- qh[b,c,l] = (sum_s A[s,l] * q[b,c,s]) * S^-0.5 ----
        const int bxq = bx - TG_BLOCKS;
        const int b = bxq >> 8;
        const int c0 = (bxq & 255) * 3;
        for (int i4 = tid; i4 < 3 * 256; i4 += 256) {
            int r = i4 >> 8, col = (i4 & 255) << 2;
            *reinterpret_cast<float4*>(&smem[r * 1024 + col]) =
                *reinterpret_cast<const float4*>(&q[((size_t)b * CC + c0 + r) * SS + col]);
        }
        __syncthreads();
        for (int idx = tid; idx < 3 * LP2; idx += 256) {
            int r = idx / LP2, l = idx % LP2;
            float val = 0.f;
            if (l < LLn) {
                int s_lo = max(0, (int)floorf(((float)l - 0.5f) * IRATIO - 0.5f) - 1);
                int s_hi = min(SS - 1, (int)ceilf(((float)l + 1.5f) * IRATIO - 0.5f) + 1);
                float a = 0.f;
                for (int s = s_lo; s <= s_hi; ++s) {
                    float src = fmaf((float)s + 0.5f, RATIO, -0.5f);
                    src = fminf(fmaxf(src, 0.f), 76.f);
                    int i0 = (int)src;
                    float w = src - (float)i0;
                    int i1 = (i0 < 76) ? i0 + 1 : 76;
                    float qv = smem[r * 1024 + s];
                    if (i0 == l) a = fmaf(1.f - w, qv, a);
                    if (i1 == l) a = fmaf(w, qv, a);
                }
                val = a * 0.03125f;   // fold 1024^-0.5
            }
            qh[((size_t)b * CC + c0 + r) * LP2 + l] = f2bf(val);
        }
    }
}

// K2: MFMA attention + fused output epilogue.
// logits(16x768) -> softmax -> u(16x80) in LDS -> out = q + gamma*interp(u) streamed.
__global__ __launch_bounds__(256, 2) void k_attn_out(const u16* __restrict__ qh,
                                                     const u16* __restrict__ tc,
                                                     const u16* __restrict__ tlc,
                                                     const float* __restrict__ q,
                                                     const float* __restrict__ gamma,
                                                     float* __restrict__ out) {
    __shared__ float pmax[4][16];
    __shared__ float psum[4][16];
    __shared__ float invl[16];
    __shared__ float us[16 * 80];
    __shared__ __align__(16) char pbuf[4][6400];   // per-wave: P bf16 [16][200] / u f32 [16][81]

    const int b = blockIdx.y;
    const int iBase = blockIdx.x * 16;
    const int tid = threadIdx.x;
    const int w = tid >> 6, lane = tid & 63;
    const int lm = lane & 15, lg = lane >> 4;

    // ---- logits: A = qh rows (3 k-steps), B = tc rows of this wave's j-slice ----
    const u16* qbase = qh + ((size_t)b * CC + iBase + lm) * LP2 + lg * 8;
    bf16x8 aq0 = *reinterpret_cast<const bf16x8*>(qbase);
    bf16x8 aq1 = *reinterpret_cast<const bf16x8*>(qbase + 32);
    bf16x8 aq2 = *reinterpret_cast<const bf16x8*>(qbase + 64);

    f32x4 acc[12];
#pragma unroll
    for (int t = 0; t < 12; ++t) acc[t] = (f32x4){0.f, 0.f, 0.f, 0.f};

    const u16* tcb = tc + ((size_t)b * CC + w * 192 + lm) * LP2 + lg * 8;
#pragma unroll
    for (int t = 0; t < 12; ++t) {
        const u16* p = tcb + (size_t)t * 16 * LP2;
        bf16x8 b0 = *reinterpret_cast<const bf16x8*>(p);
        bf16x8 b1 = *reinterpret_cast<const bf16x8*>(p + 32);
        bf16x8 b2 = *reinterpret_cast<const bf16x8*>(p + 64);
        acc[t] = __builtin_amdgcn_mfma_f32_16x16x32_bf16(aq0, b0, acc[t], 0, 0, 0);
        acc[t] = __builtin_amdgcn_mfma_f32_16x16x32_bf16(aq1, b1, acc[t], 0, 0, 0);
        acc[t] = __builtin_amdgcn_mfma_f32_16x16x32_bf16(aq2, b2, acc[t], 0, 0, 0);
    }

    // ---- softmax (C layout: col = lane&15, row = lg*4 + reg) ----
    float m[4];
#pragma unroll
    for (int r = 0; r < 4; ++r) {
        float mm = acc[0][r];
#pragma unroll
        for (int t = 1; t < 12; ++t) mm = fmaxf(mm, acc[t][r]);
#pragma unroll
        for (int off = 8; off >= 1; off >>= 1) mm = fmaxf(mm, __shfl_xor(mm, off));
        m[r] = mm;
    }
    if (lm == 0) {
#pragma unroll
        for (int r = 0; r < 4; ++r) pmax[w][lg * 4 + r] = m[r];
    }
    __syncthreads();
    float gm[4];
#pragma unroll
    for (int r = 0; r < 4; ++r) {
        int row = lg * 4 + r;
        gm[r] = fmaxf(fmaxf(pmax[0][row], pmax[1][row]), fmaxf(pmax[2][row], pmax[3][row]));
    }
    float s[4] = {0.f, 0.f, 0.f, 0.f};
#pragma unroll
    for (int t = 0; t < 12; ++t) {
#pragma unroll
        for (int r = 0; r < 4; ++r) {
            float e = __expf(acc[t][r] - gm[r]);
            acc[t][r] = e;
            s[r] += e;
        }
    }
#pragma unroll
    for (int r = 0; r < 4; ++r) {
#pragma unroll
        for (int off = 8; off >= 1; off >>= 1) s[r] += __shfl_xor(s[r], off);
    }
    if (lm == 0) {
#pragma unroll
        for (int r = 0; r < 4; ++r) psum[w][lg * 4 + r] = s[r];
    }
    __syncthreads();
    if (w == 0 && lm == 0) {
#pragma unroll
        for (int r = 0; r < 4; ++r) {
            int row = lg * 4 + r;
            invl[row] = 1.0f / (psum[0][row] + psum[1][row] + psum[2][row] + psum[3][row]);
        }
    }

    // ---- P -> bf16 into per-wave LDS (stride 200 halves) ----
    u16* P = (u16*)pbuf[w];
#pragma unroll
    for (int t = 0; t < 12; ++t) {
#pragma unroll
        for (int r = 0; r < 4; ++r)
            P[(lg * 4 + r) * 200 + t * 16 + lm] = f2bf(acc[t][r]);
    }

    // ---- PV: u[16 x 80] += P[16 x 192] . tlc[192 x 80] ----
    f32x4 u[5];
#pragma unroll
    for (int nt = 0; nt < 5; ++nt) u[nt] = (f32x4){0.f, 0.f, 0.f, 0.f};
    const u16* tb = tlc + ((size_t)b * LP + lm) * CC + w * 192 + lg * 8;
#pragma unroll
    for (int ks = 0; ks < 6; ++ks) {
        bf16x8 pa = *reinterpret_cast<const bf16x8*>(&P[lm * 200 + ks * 32 + lg * 8]);
#pragma unroll
        for (int nt = 0; nt < 5; ++nt) {
            bf16x8 bv = *reinterpret_cast<const bf16x8*>(tb + (size_t)nt * 16 * CC + ks * 32);
            u[nt] = __builtin_amdgcn_mfma_f32_16x16x32_bf16(pa, bv, u[nt], 0, 0, 0);
        }
    }

    // ---- cross-wave u reduce into us[16][80] (alias P buffer) ----
    float* up = (float*)pbuf[w];
#pragma unroll
    for (int nt = 0; nt < 5; ++nt) {
#pragma unroll
        for (int r = 0; r < 4; ++r)
            up[(lg * 4 + r) * 81 + nt * 16 + lm] = u[nt][r];
    }
    __syncthreads();
#pragma unroll
    for (int k = 0; k < 5; ++k) {
        int idx = tid + (k << 8);
        int row = idx / LP, l = idx % LP;
        float v = ((float*)pbuf[0])[row * 81 + l] + ((float*)pbuf[1])[row * 81 + l]
                + ((float*)pbuf[2])[row * 81 + l] + ((float*)pbuf[3])[row * 81 + l];
        us[row * LP + l] = v * invl[row];
    }
    __syncthreads();

    // ---- epilogue: out = q + gamma * interp(u) for these 16 channel rows ----
    const float g = gamma[0];
    const int s0 = tid * 4;
    int i0x[4], i1x[4];
    float wx[4];
#pragma unroll
    for (int k = 0; k < 4; ++k) {
        float src = fmaf((float)(s0 + k) + 0.5f, RATIO, -0.5f);
        src = fminf(fmaxf(src, 0.f), 76.f);
        i0x[k] = (int)src;
        wx[k] = src - (float)i0x[k];
        i1x[k] = (i0x[k] < 76) ? i0x[k] + 1 : 76;
    }
    const size_t rowBase = ((size_t)b * CC + iBase) * SS + s0;
#pragma unroll 2
    for (int r = 0; r < 16; ++r) {
        const size_t base = rowBase + (size_t)r * SS;
        float4 qv = *reinterpret_cast<const float4*>(&q[base]);
        const float* ur = &us[r * LP];
        float rr[4];
        const float* qp = reinterpret_cast<const float*>(&qv);
#pragma unroll
        for (int k = 0; k < 4; ++k) {
            float uv = fmaf(1.f - wx[k], ur[i0x[k]], wx[k] * ur[i1x[k]]);
            rr[k] = qp[k] + g * uv;
        }
        *reinterpret_cast<float4*>(&out[base]) = make_float4(rr[0], rr[1], rr[2], rr[3]);
    }
}

extern "C" void kernel_launch(void* const* d_in, const int* in_sizes, int n_in,
                              void* d_out, int out_size, void* d_ws, size_t ws_size,
                              hipStream_t stream) {
    const float* img   = (const float*)d_in[0];
    const float* text  = (const float*)d_in[1];
    const float* Wt    = (const float*)d_in[2];
    const float* gamma = (const float*)d_in[3];
    float* out = (float*)d_out;
    char* ws = (char*)d_ws;
    u16*   tc_bf  = (u16*)(ws);                   // 32*768*96*2 = 4,718,592
    u16*   tlc_bf = (u16*)(ws + 4718592);         // 32*80*768*2 = 3,932,160
    u16*   qh_bf  = (u16*)(ws + 8650752);         // 32*768*96*2 = 4,718,592
    u16*   At_bf  = (u16*)(ws + 13369344);        // 32*80*512*2 = 2,621,440
    u16*   Wb_bf  = (u16*)(ws + 15990784);        // 768*512*2   =   786,432  (end 16,777,216)

    k_cvt<<<dim3(CVT_TXT_BLOCKS + CVT_W_BLOCKS), 256, 0, stream>>>(text, Wt, At_bf, Wb_bf);
    k_mid<<<dim3(TG_BLOCKS + QH_BLOCKS), 256, 0, stream>>>(img, At_bf, Wb_bf, qh_bf, tc_bf, tlc_bf);
    k_attn_out<<<dim3(48, BB), 256, 0, stream>>>(qh_bf, tc_bf, tlc_bf, img, gamma, out);
}

// Round 7
// 100.299 us; speedup vs baseline: 1.7612x; 1.2808x over previous
//
#include <hip/hip_runtime.h>

#define BB 32
#define CC 768
#define SS 1024
#define LLn 77
#define DD 512
#define LP 80      // padded L for tlc rows / At rows
#define LP2 96     // padded L (K dim) for bf16 MFMA operands, mult of 32

#define RATIO 0.0751953125f   // 77/1024 exact in fp32
#define IRATIO 13.298701f     // ~1024/77 (only used for conservative loop bounds)

#define CVT_TXT_BLOCKS (BB * LP * DD / 4 / 256)   // 1280
#define CVT_W_BLOCKS ((CC / 32) * (DD / 32))      // 384
#define TG_BLOCKS (BB * 5 * 4)                    // 640
#define QH_BLOCKS (256 * BB)                      // 8192

typedef short bf16x8 __attribute__((ext_vector_type(8)));
typedef float f32x4 __attribute__((ext_vector_type(4)));
typedef unsigned short u16;

__device__ __forceinline__ u16 f2bf(float f) {
    unsigned int u; __builtin_memcpy(&u, &f, 4);
    u += 0x7fffu + ((u >> 16) & 1u);   // RNE
    return (u16)(u >> 16);
}

// K0: tiny converts. text[b,77,512] f32 -> At[b,80,512] bf16 (pad rows zero);
//     W[d,c] f32 -> Wb[c,d] bf16 transposed.
__global__ __launch_bounds__(256) void k_cvt(const float* __restrict__ text,
                                             const float* __restrict__ Wt,
                                             u16* __restrict__ At,
                                             u16* __restrict__ Wb) {
    __shared__ float tile[32 * 33];
    const int bx = blockIdx.x;
    const int tid = threadIdx.x;
    if (bx < CVT_TXT_BLOCKS) {
        int j = bx * 256 + tid;                    // float4-granular, exact cover
        int row80 = j >> 7, col4 = (j & 127) << 2;
        int b = row80 / LP, l = row80 - b * LP;
        u16 o[4] = {0, 0, 0, 0};
        if (l < LLn) {
            float4 v = *reinterpret_cast<const float4*>(&text[((size_t)b * LLn + l) * DD + col4]);
            o[0] = f2bf(v.x); o[1] = f2bf(v.y); o[2] = f2bf(v.z); o[3] = f2bf(v.w);
        }
        *reinterpret_cast<uint2*>(&At[(size_t)row80 * DD + col4]) = *reinterpret_cast<uint2*>(o);
    } else {
        const int bw = bx - CVT_TXT_BLOCKS;
        const int c0 = (bw % (CC / 32)) * 32, d0 = (bw / (CC / 32)) * 32;
        const int tx = tid & 31, ty = tid >> 5;    // ty 0..7
#pragma unroll
        for (int k = 0; k < 4; ++k) {
            int d = ty + k * 8;
            tile[d * 33 + tx] = Wt[(size_t)(d0 + d) * CC + c0 + tx];
        }
        __syncthreads();
#pragma unroll
        for (int k = 0; k < 4; ++k) {
            int c = ty + k * 8;
            Wb[(size_t)(c0 + c) * DD + d0 + tx] = f2bf(tile[tx * 33 + c]);
        }
    }
}

// K1: fused tgemm (640 blocks, first) + qh-interp (8192 blocks). Independent work.
__global__ __launch_bounds__(256) void k_mid(const float* __restrict__ q,
                                             const u16* __restrict__ At,
                                             const u16* __restrict__ Wb,
                                             u16* __restrict__ qh,
                                             u16* __restrict__ tc,
                                             u16* __restrict__ tlc) {
    __shared__ float smem[3 * 1024];
    const int bx = blockIdx.x;
    const int tid = threadIdx.x;

    if (bx < TG_BLOCKS) {
        // ---- t = text @ W, batch-aligned tiles. bx -> (colgroup, b, tile) ----
        const int cg = bx / 160, mt = bx % 160;
        const int b = mt / 5, tile = mt % 5;
        const int l0 = tile * 16;
        const int w = tid >> 6, lane = tid & 63;
        const int lm = lane & 15, lg = lane >> 4;
        const int c0 = cg * 192 + w * 48;

        f32x4 acc[3];
#pragma unroll
        for (int nt = 0; nt < 3; ++nt) acc[nt] = (f32x4){0.f, 0.f, 0.f, 0.f};

        const u16* ap = At + ((size_t)b * LP + l0 + lm) * DD + lg * 8;
        const u16* bp = Wb + (size_t)(c0 + lm) * DD + lg * 8;
#pragma unroll 4
        for (int ks = 0; ks < 16; ++ks) {
            bf16x8 aq = *reinterpret_cast<const bf16x8*>(ap + ks * 32);
#pragma unroll
            for (int nt = 0; nt < 3; ++nt) {
                bf16x8 bv = *reinterpret_cast<const bf16x8*>(bp + (size_t)nt * 16 * DD + ks * 32);
                acc[nt] = __builtin_amdgcn_mfma_f32_16x16x32_bf16(aq, bv, acc[nt], 0, 0, 0);
            }
        }

        const int lq = l0 + lg * 4;   // quad start (pad rows produce zero acc)
#pragma unroll
        for (int nt = 0; nt < 3; ++nt) {
            int c = c0 + nt * 16 + lm;
            u16 pk[4];
#pragma unroll
            for (int r = 0; r < 4; ++r) pk[r] = f2bf(acc[nt][r]);
            uint2 pv; __builtin_memcpy(&pv, pk, 8);
            *reinterpret_cast<uint2*>(&tc[((size_t)b * CC + c) * LP2 + lq]) = pv;  // 8B aligned
#pragma unroll
            for (int r = 0; r < 4; ++r)
                tlc[((size_t)b * LP + lq + r) * CC + c] = pk[r];
        }
        if (tile == 4 && lg == 0) {   // zero tc K-pad l=80..95
            uint4 z = {0u, 0u, 0u, 0u};
#pragma unroll
            for (int nt = 0; nt < 3; ++nt) {
                int c = c0 + nt * 16 + lm;
                *reinterpret_cast<uint4*>(&tc[((size_t)b * CC + c) * LP2 + 80]) = z;
                *reinterpret_cast<uint4*>(&tc[((size_t)b * CC + c) * LP2 + 88]) = z;
            }
        }
    } else {
        // ---- qh[b,c,l] = (sum_s A[s,l] * q[b,c,s]) * S^-0.5, tent-filter form ----
        const int bxq = bx - TG_BLOCKS;
        const int b = bxq >> 8;
        const int c0 = (bxq & 255) * 3;
        for (int i4 = tid; i4 < 3 * 256; i4 += 256) {
            int r = i4 >> 8, col = (i4 & 255) << 2;
            *reinterpret_cast<float4*>(&smem[r * 1024 + col]) =
                *reinterpret_cast<const float4*>(&q[((size_t)b * CC + c0 + r) * SS + col]);
        }
        __syncthreads();
        for (int idx = tid; idx < 3 * LP2; idx += 256) {
            int r = idx / LP2, l = idx % LP2;
            float val = 0.f;
            if (l < LLn) {
                int s_lo = max(0, (int)floorf(((float)l - 0.5f) * IRATIO - 0.5f) - 1);
                int s_hi = min(SS - 1, (int)ceilf(((float)l + 1.5f) * IRATIO - 0.5f) + 1);
                float fl = (float)l;
                float a = 0.f;
                for (int s = s_lo; s <= s_hi; ++s) {
                    float src = fmaf((float)s + 0.5f, RATIO, -0.5f);
                    src = fminf(fmaxf(src, 0.f), 76.f);
                    float wgt = fmaxf(0.f, 1.f - fabsf(src - fl));   // tent == linear interp weight
                    a = fmaf(wgt, smem[r * 1024 + s], a);
                }
                val = a * 0.03125f;   // fold 1024^-0.5
            }
            qh[((size_t)b * CC + c0 + r) * LP2 + l] = f2bf(val);
        }
    }
}

// K2: MFMA attention + fused output epilogue, with early q-prefetch (T14) and NT stores.
__global__ __launch_bounds__(256, 2) void k_attn_out(const u16* __restrict__ qh,
                                                     const u16* __restrict__ tc,
                                                     const u16* __restrict__ tlc,
                                                     const float* __restrict__ q,
                                                     const float* __restrict__ gamma,
                                                     float* __restrict__ out) {
    __shared__ float pmax[4][16];
    __shared__ float psum[4][16];
    __shared__ float us[16 * 80];
    __shared__ __align__(16) char pbuf[4][6400];   // per-wave: P bf16 [16][200] / u f32 [16][81]

    const int b = blockIdx.y;
    const int iBase = blockIdx.x * 16;
    const int tid = threadIdx.x;
    const int w = tid >> 6, lane = tid & 63;
    const int lm = lane & 15, lg = lane >> 4;
    const float g = gamma[0];

    // ---- logits: A = qh rows (3 k-steps), B = tc rows of this wave's j-slice ----
    const u16* qbase = qh + ((size_t)b * CC + iBase + lm) * LP2 + lg * 8;
    bf16x8 aq0 = *reinterpret_cast<const bf16x8*>(qbase);
    bf16x8 aq1 = *reinterpret_cast<const bf16x8*>(qbase + 32);
    bf16x8 aq2 = *reinterpret_cast<const bf16x8*>(qbase + 64);

    f32x4 acc[12];
#pragma unroll
    for (int t = 0; t < 12; ++t) acc[t] = (f32x4){0.f, 0.f, 0.f, 0.f};

    const u16* tcb = tc + ((size_t)b * CC + w * 192 + lm) * LP2 + lg * 8;
#pragma unroll
    for (int t = 0; t < 12; ++t) {
        const u16* p = tcb + (size_t)t * 16 * LP2;
        bf16x8 b0 = *reinterpret_cast<const bf16x8*>(p);
        bf16x8 b1 = *reinterpret_cast<const bf16x8*>(p + 32);
        bf16x8 b2 = *reinterpret_cast<const bf16x8*>(p + 64);
        acc[t] = __builtin_amdgcn_mfma_f32_16x16x32_bf16(aq0, b0, acc[t], 0, 0, 0);
        acc[t] = __builtin_amdgcn_mfma_f32_16x16x32_bf16(aq1, b1, acc[t], 0, 0, 0);
        acc[t] = __builtin_amdgcn_mfma_f32_16x16x32_bf16(aq2, b2, acc[t], 0, 0, 0);
    }

    // ---- T14: prefetch this block's 16 q rows now; latency hides under softmax+PV ----
    const size_t qBase = ((size_t)b * CC + iBase) * SS + (size_t)(tid << 2);
    f32x4 qreg[16];
#pragma unroll
    for (int r = 0; r < 16; ++r)
        qreg[r] = *reinterpret_cast<const f32x4*>(&q[qBase + (size_t)r * SS]);

    // ---- softmax (C layout: col = lane&15, row = lg*4 + reg) ----
    float m[4];
#pragma unroll
    for (int r = 0; r < 4; ++r) {
        float mm = acc[0][r];
#pragma unroll
        for (int t = 1; t < 12; ++t) mm = fmaxf(mm, acc[t][r]);
#pragma unroll
        for (int off = 8; off >= 1; off >>= 1) mm = fmaxf(mm, __shfl_xor(mm, off));
        m[r] = mm;
    }
    if (lm == 0) {
#pragma unroll
        for (int r = 0; r < 4; ++r) pmax[w][lg * 4 + r] = m[r];
    }
    __syncthreads();   // A: pmax visible
    float gm[4];
#pragma unroll
    for (int r = 0; r < 4; ++r) {
        int row = lg * 4 + r;
        gm[r] = fmaxf(fmaxf(pmax[0][row], pmax[1][row]), fmaxf(pmax[2][row], pmax[3][row]));
    }
    float s[4] = {0.f, 0.f, 0.f, 0.f};
#pragma unroll
    for (int t = 0; t < 12; ++t) {
#pragma unroll
        for (int r = 0; r < 4; ++r) {
            float e = __expf(acc[t][r] - gm[r]);
            acc[t][r] = e;
            s[r] += e;
        }
    }
#pragma unroll
    for (int r = 0; r < 4; ++r) {
#pragma unroll
        for (int off = 8; off >= 1; off >>= 1) s[r] += __shfl_xor(s[r], off);
    }
    if (lm == 0) {
#pragma unroll
        for (int r = 0; r < 4; ++r) psum[w][lg * 4 + r] = s[r];
    }

    // ---- P -> bf16 into per-wave LDS (stride 200 halves); no barrier needed (wave-private) ----
    u16* P = (u16*)pbuf[w];
#pragma unroll
    for (int t = 0; t < 12; ++t) {
#pragma unroll
        for (int r = 0; r < 4; ++r)
            P[(lg * 4 + r) * 200 + t * 16 + lm] = f2bf(acc[t][r]);
    }

    // ---- PV: u[16 x 80] += P[16 x 192] . tlc[192 x 80] ----
    f32x4 u[5];
#pragma unroll
    for (int nt = 0; nt < 5; ++nt) u[nt] = (f32x4){0.f, 0.f, 0.f, 0.f};
    const u16* tb = tlc + ((size_t)b * LP + lm) * CC + w * 192 + lg * 8;
#pragma unroll
    for (int ks = 0; ks < 6; ++ks) {
        bf16x8 pa = *reinterpret_cast<const bf16x8*>(&P[lm * 200 + ks * 32 + lg * 8]);
#pragma unroll
        for (int nt = 0; nt < 5; ++nt) {
            bf16x8 bv = *reinterpret_cast<const bf16x8*>(tb + (size_t)nt * 16 * CC + ks * 32);
            u[nt] = __builtin_amdgcn_mfma_f32_16x16x32_bf16(pa, bv, u[nt], 0, 0, 0);
        }
    }

    // ---- cross-wave u reduce (alias P buffer; wave-local reuse is ordered) ----
    float* up = (float*)pbuf[w];
#pragma unroll
    for (int nt = 0; nt < 5; ++nt) {
#pragma unroll
        for (int r = 0; r < 4; ++r)
            up[(lg * 4 + r) * 81 + nt * 16 + lm] = u[nt][r];
    }
    __syncthreads();   // B: all u partials + psum visible
#pragma unroll
    for (int k = 0; k < 5; ++k) {
        int idx = tid + (k << 8);
        int row = idx / LP, l = idx % LP;
        float v = ((float*)pbuf[0])[row * 81 + l] + ((float*)pbuf[1])[row * 81 + l]
                + ((float*)pbuf[2])[row * 81 + l] + ((float*)pbuf[3])[row * 81 + l];
        float denom = psum[0][row] + psum[1][row] + psum[2][row] + psum[3][row];
        us[row * LP + l] = v / denom;
    }
    __syncthreads();   // C: us ready

    // ---- epilogue: out = qreg + gamma * interp(us), nontemporal stores ----
    const int s0 = tid << 2;
    int i0x[4], i1x[4];
    float wx[4];
#pragma unroll
    for (int k = 0; k < 4; ++k) {
        float src = fmaf((float)(s0 + k) + 0.5f, RATIO, -0.5f);
        src = fminf(fmaxf(src, 0.f), 76.f);
        i0x[k] = (int)src;
        wx[k] = src - (float)i0x[k];
        i1x[k] = (i0x[k] < 76) ? i0x[k] + 1 : 76;
    }
#pragma unroll
    for (int r = 0; r < 16; ++r) {
        const float* ur = &us[r * LP];
        f32x4 o;
#pragma unroll
        for (int k = 0; k < 4; ++k) {
            float uv = fmaf(1.f - wx[k], ur[i0x[k]], wx[k] * ur[i1x[k]]);
            o[k] = qreg[r][k] + g * uv;
        }
        __builtin_nontemporal_store(o, reinterpret_cast<f32x4*>(&out[qBase + (size_t)r * SS]));
    }
}

extern "C" void kernel_launch(void* const* d_in, const int* in_sizes, int n_in,
                              void* d_out, int out_size, void* d_ws, size_t ws_size,
                              hipStream_t stream) {
    const float* img   = (const float*)d_in[0];
    const float* text  = (const float*)d_in[1];
    const float* Wt    = (const float*)d_in[2];
    const float* gamma = (const float*)d_in[3];
    float* out = (float*)d_out;
    char* ws = (char*)d_ws;
    u16*   tc_bf  = (u16*)(ws);                   // 32*768*96*2 = 4,718,592
    u16*   tlc_bf = (u16*)(ws + 4718592);         // 32*80*768*2 = 3,932,160
    u16*   qh_bf  = (u16*)(ws + 8650752);         // 32*768*96*2 = 4,718,592
    u16*   At_bf  = (u16*)(ws + 13369344);        // 32*80*512*2 = 2,621,440
    u16*   Wb_bf  = (u16*)(ws + 15990784);        // 768*512*2   =   786,432  (end 16,777,216)

    k_cvt<<<dim3(CVT_TXT_BLOCKS + CVT_W_BLOCKS), 256, 0, stream>>>(text, Wt, At_bf, Wb_bf);
    k_mid<<<dim3(TG_BLOCKS + QH_BLOCKS), 256, 0, stream>>>(img, At_bf, Wb_bf, qh_bf, tc_bf, tlc_bf);
    k_attn_out<<<dim3(48, BB), 256, 0, stream>>>(qh_bf, tc_bf, tlc_bf, img, gamma, out);
}